// Round 1
// baseline (603.890 us; speedup 1.0000x reference)
//
#include <hip/hip_runtime.h>
#include <cmath>

// ---------------------------------------------------------------------------
// Problem constants: B=16, N=196, D=512, M=20, H=8, hd=64, k=51
//   tokens = 3136, 3D = 1536
// ---------------------------------------------------------------------------

// Generic small GEMM, fp32 storage, fp32 FMA with fp64 chunk accumulation.
// C[i,j] = sum_k A[i,k] * B'[k,j]  (+bias[j]) (+res[i*ldc+j])
//   bTrans=1: B is [N][K] row-major (we dot rows)      -> B'[k,j] = B[j*ldb+k]
//   bTrans=0: B is [K][N] row-major                    -> B'[k,j] = B[k*ldb+j]
// Batched via blockIdx.z: off = (z/zInner)*Outer + (z%zInner)*Inner per operand.
__global__ __launch_bounds__(256) void gemm_kernel(
    const float* __restrict__ A, const float* __restrict__ B,
    float* __restrict__ C, const float* __restrict__ bias,
    const float* __restrict__ res,
    int M, int N, int K, int lda, int ldb, int ldc,
    int zInner, long long aOuter, long long aInner,
    long long bOuter, long long bInner,
    long long cOuter, long long cInner, int bTrans)
{
  int z = blockIdx.z;
  int zo = z / zInner, zi = z % zInner;
  A += zo * aOuter + zi * aInner;
  B += zo * bOuter + zi * bInner;
  C += zo * cOuter + zi * cInner;

  __shared__ __align__(16) float As[16][68];
  __shared__ __align__(16) float Bs[16][68];

  int tid = threadIdx.x;
  int tx = tid & 15, ty = tid >> 4;
  int i0 = blockIdx.x * 64, j0 = blockIdx.y * 64;

  double acc[4][4];
#pragma unroll
  for (int i = 0; i < 4; i++)
#pragma unroll
    for (int j = 0; j < 4; j++) acc[i][j] = 0.0;

  for (int k0 = 0; k0 < K; k0 += 16) {
    // stage A tile [64 rows][16 k] -> As[k][row]
#pragma unroll
    for (int rr = 0; rr < 4; rr++) {
      int r = ty + 16 * rr;
      int gi = i0 + r, gk = k0 + tx;
      As[tx][r] = (gi < M && gk < K) ? A[(size_t)gi * lda + gk] : 0.0f;
    }
    if (bTrans) {
#pragma unroll
      for (int rr = 0; rr < 4; rr++) {
        int r = ty + 16 * rr;
        int gj = j0 + r, gk = k0 + tx;
        Bs[tx][r] = (gj < N && gk < K) ? B[(size_t)gj * ldb + gk] : 0.0f;
      }
    } else {
      int j = tid & 63, c0 = (tid >> 6) * 4;
#pragma unroll
      for (int cc = 0; cc < 4; cc++) {
        int c = c0 + cc;
        int gk = k0 + c, gj = j0 + j;
        Bs[c][j] = (gk < K && gj < N) ? B[(size_t)gk * ldb + gj] : 0.0f;
      }
    }
    __syncthreads();

    float cf[4][4];
#pragma unroll
    for (int i = 0; i < 4; i++)
#pragma unroll
      for (int j = 0; j < 4; j++) cf[i][j] = 0.0f;
#pragma unroll
    for (int kk = 0; kk < 16; kk++) {
      float4 a4 = *(const float4*)&As[kk][ty * 4];
      float4 b4 = *(const float4*)&Bs[kk][tx * 4];
      float av[4] = {a4.x, a4.y, a4.z, a4.w};
      float bv[4] = {b4.x, b4.y, b4.z, b4.w};
#pragma unroll
      for (int i = 0; i < 4; i++)
#pragma unroll
        for (int j = 0; j < 4; j++) cf[i][j] = fmaf(av[i], bv[j], cf[i][j]);
    }
#pragma unroll
    for (int i = 0; i < 4; i++)
#pragma unroll
      for (int j = 0; j < 4; j++) acc[i][j] += (double)cf[i][j];
    __syncthreads();
  }

#pragma unroll
  for (int i = 0; i < 4; i++) {
    int gi = i0 + ty * 4 + i;
    if (gi >= M) continue;
    int gj0 = j0 + tx * 4;
    if (gj0 >= N) continue;  // all our N are multiples of 4
    float ov[4];
#pragma unroll
    for (int j = 0; j < 4; j++) {
      double v = acc[i][j];
      if (bias) v += (double)bias[gj0 + j];
      if (res)  v += (double)res[(size_t)gi * ldc + gj0 + j];
      ov[j] = (float)v;
    }
    float4 o; o.x = ov[0]; o.y = ov[1]; o.z = ov[2]; o.w = ov[3];
    *(float4*)&C[(size_t)gi * ldc + gj0] = o;
  }
}

// In-place row softmax of scaled scores: rows of length 196, scale 1/sqrt(64).
// One wave per row, 4 rows per block. fp64 internal.
__global__ __launch_bounds__(256) void softmax_kernel(float* __restrict__ S)
{
  int row = blockIdx.x * 4 + (threadIdx.x >> 6);
  int lane = threadIdx.x & 63;
  float* sr = S + (size_t)row * 196;
  double v[4];
#pragma unroll
  for (int t = 0; t < 4; t++) {
    int j = lane + 64 * t;
    v[t] = (j < 196) ? (double)sr[j] * 0.125 : -1e300;
  }
  double mx = fmax(fmax(v[0], v[1]), fmax(v[2], v[3]));
#pragma unroll
  for (int off = 1; off < 64; off <<= 1) mx = fmax(mx, __shfl_xor(mx, off));
  double e[4]; double s = 0.0;
#pragma unroll
  for (int t = 0; t < 4; t++) {
    int j = lane + 64 * t;
    e[t] = (j < 196) ? exp(v[t] - mx) : 0.0;
    s += e[t];
  }
#pragma unroll
  for (int off = 1; off < 64; off <<= 1) s += __shfl_xor(s, off);
  double inv = 1.0 / s;
#pragma unroll
  for (int t = 0; t < 4; t++) {
    int j = lane + 64 * t;
    if (j < 196) sr[j] = (float)(e[t] * inv);
  }
}

// In-place LayerNorm (ddof=0, eps=1e-5) + exact GELU over rows of 512.
__global__ __launch_bounds__(256) void lngelu_kernel(float* __restrict__ H,
    const float* __restrict__ g, const float* __restrict__ bb)
{
  int row = blockIdx.x;
  float* hr = H + (size_t)row * 512;
  int tid = threadIdx.x, lane = tid & 63, wv = tid >> 6;
  __shared__ double red[8];
  double x0 = (double)hr[tid], x1 = (double)hr[tid + 256];
  double s = x0 + x1;
#pragma unroll
  for (int off = 1; off < 64; off <<= 1) s += __shfl_xor(s, off);
  if (lane == 0) red[wv] = s;
  __syncthreads();
  double mu = (red[0] + red[1] + red[2] + red[3]) * (1.0 / 512.0);
  double d0 = x0 - mu, d1 = x1 - mu;
  double q = d0 * d0 + d1 * d1;
#pragma unroll
  for (int off = 1; off < 64; off <<= 1) q += __shfl_xor(q, off);
  if (lane == 0) red[4 + wv] = q;
  __syncthreads();
  double var = (red[4] + red[5] + red[6] + red[7]) * (1.0 / 512.0);
  double inv = 1.0 / sqrt(var + 1e-5);
  double y0 = d0 * inv * (double)g[tid]       + (double)bb[tid];
  double y1 = d1 * inv * (double)g[tid + 256] + (double)bb[tid + 256];
  const double ISQRT2 = 0.70710678118654752440;
  double z0 = 0.5 * y0 * (1.0 + erf(y0 * ISQRT2));
  double z1 = 0.5 * y1 * (1.0 + erf(y1 * ISQRT2));
  hr[tid] = (float)z0;
  hr[tid + 256] = (float)z1;
}

// Qp[token,m] = h[token,:] . w2[m,:] + b2[m] ; fp64 accumulate. 62720 outputs.
__global__ __launch_bounds__(256) void w2_kernel(const float* __restrict__ H,
    const float* __restrict__ W2, const float* __restrict__ B2,
    float* __restrict__ Qp)
{
  int gidx = blockIdx.x * 256 + threadIdx.x;  // grid 245*256 == 62720 exactly
  int token = gidx / 20, m = gidx % 20;
  const float* hr = H + (size_t)token * 512;
  const float* wr = W2 + (size_t)m * 512;
  double acc = 0.0;
  for (int k = 0; k < 512; k += 4) {
    float4 hv = *(const float4*)&hr[k];
    float4 wv = *(const float4*)&wr[k];
    acc += (double)hv.x * wv.x + (double)hv.y * wv.y +
           (double)hv.z * wv.z + (double)hv.w * wv.w;
  }
  Qp[gidx] = (float)(acc + (double)B2[m]);
}

// Final: per (b,n,m) abs-top-51 over D of A = (F*T)*Qp, 0/1 mask, L2-normalize,
// write out[b,n,d,m]. Selection key = exact double product |F*T| (bit-exact vs
// a float64 reference), tie-break by lower d via ballot ranks.
__global__ __launch_bounds__(256) void topk_kernel(
    const float* __restrict__ F, const float* __restrict__ T,
    const float* __restrict__ Qp, float* __restrict__ out)
{
  const int KSEL = 51;
  int bn = blockIdx.x;
  int tid = threadIdx.x, lane = tid & 63, wv = tid >> 6;
  __shared__ float tile[512 * 21];  // [d][m], padded row stride 21
  const float* Frow = F + (size_t)bn * 512;
  double f[8];
#pragma unroll
  for (int s = 0; s < 8; s++) f[s] = (double)Frow[lane + 64 * s];

  for (int m = wv; m < 20; m += 4) {
    double qp = (double)Qp[(size_t)bn * 20 + m];
    const float* Trow = T + (size_t)m * 512;
    double a[8];
    unsigned long long u[8];
#pragma unroll
    for (int s = 0; s < 8; s++) {
      double p = f[s] * (double)Trow[lane + 64 * s];  // exact in fp64
      a[s] = p * qp;
      u[s] = ((unsigned long long)__double_as_longlong(p)) & 0x7fffffffffffffffULL;
    }
    // binary search smallest threshold with count(u >= thr) >= 51
    unsigned long long lo = 0ULL, hi = 0x7ff0000000000000ULL;
    while (hi - lo > 1ULL) {
      unsigned long long mid = lo + ((hi - lo) >> 1);
      int c = 0;
#pragma unroll
      for (int s = 0; s < 8; s++) c += (u[s] >= mid) ? 1 : 0;
#pragma unroll
      for (int off = 1; off < 64; off <<= 1) c += __shfl_xor(c, off);
      if (c >= KSEL) { lo = mid; if (c == KSEL) break; }
      else hi = mid;
    }
    unsigned long long thr = lo;
    int cg = 0;
#pragma unroll
    for (int s = 0; s < 8; s++) cg += (u[s] > thr) ? 1 : 0;
#pragma unroll
    for (int off = 1; off < 64; off <<= 1) cg += __shfl_xor(cg, off);
    int need_eq = KSEL - cg;  // how many ==thr to take, in increasing d order
    unsigned long long lmask = (1ULL << lane) - 1ULL;
    bool sel[8];
    int base = 0;
#pragma unroll
    for (int s = 0; s < 8; s++) {   // d = lane + 64*s: (s,lane) lexicographic == d order
      bool iseq = (u[s] == thr);
      unsigned long long bal = __ballot((int)iseq);
      int rk = base + __popcll(bal & lmask);
      sel[s] = (u[s] > thr) || (iseq && rk < need_eq);
      base += __popcll(bal);
    }
    double ss = 0.0;
#pragma unroll
    for (int s = 0; s < 8; s++) if (sel[s]) ss += a[s] * a[s];
#pragma unroll
    for (int off = 1; off < 64; off <<= 1) ss += __shfl_xor(ss, off);
    double inv = 1.0 / fmax(sqrt(ss), 1e-6);
#pragma unroll
    for (int s = 0; s < 8; s++)
      tile[(lane + 64 * s) * 21 + m] = sel[s] ? (float)(a[s] * inv) : 0.0f;
  }
  __syncthreads();

  // coalesced writeout: [512][20] contiguous per (b,n)
  float* orow = out + (size_t)bn * 10240;
#pragma unroll
  for (int it = 0; it < 10; it++) {
    int i = it * 256 + tid;  // float4 index, 2560 total
    int j = i * 4;
    float4 o;
    o.x = tile[((j + 0) / 20) * 21 + (j + 0) % 20];
    o.y = tile[((j + 1) / 20) * 21 + (j + 1) % 20];
    o.z = tile[((j + 2) / 20) * 21 + (j + 2) % 20];
    o.w = tile[((j + 3) / 20) * 21 + (j + 3) % 20];
    *(float4*)&orow[j] = o;
  }
}

extern "C" void kernel_launch(void* const* d_in, const int* in_sizes, int n_in,
                              void* d_out, int out_size, void* d_ws, size_t ws_size,
                              hipStream_t stream) {
  const float* F    = (const float*)d_in[0];   // [3136,512]
  const float* Wqkv = (const float*)d_in[1];   // [1536,512]
  const float* bqkv = (const float*)d_in[2];   // [1536]
  const float* Wo   = (const float*)d_in[3];   // [512,512]
  const float* bo   = (const float*)d_in[4];   // [512]
  const float* W1   = (const float*)d_in[5];   // [512,512]
  const float* b1   = (const float*)d_in[6];   // [512]
  const float* lng  = (const float*)d_in[7];   // [512]
  const float* lnb  = (const float*)d_in[8];   // [512]
  const float* W2   = (const float*)d_in[9];   // [20,512]
  const float* b2   = (const float*)d_in[10];  // [20]
  const float* Tm   = (const float*)d_in[11];  // [20,512]
  float* out = (float*)d_out;

  float* ws     = (float*)d_ws;
  float* qkv    = ws;                    // 3136*1536 = 4,816,896
  float* scores = qkv + 4816896;         // 128*196*196 = 4,917,248
  float* Omg    = scores + 4917248;      // 3136*512
  float* Fenh   = Omg + 1605632;         // 3136*512
  float* h1     = Fenh + 1605632;        // 3136*512
  float* Qp     = h1 + 1605632;          // 3136*20
  dim3 blk(256);

  // 1) qkv = F @ Wqkv^T + bqkv               [3136,1536]
  gemm_kernel<<<dim3(49, 24, 1), blk, 0, stream>>>(
      F, Wqkv, qkv, bqkv, nullptr,
      3136, 1536, 512, 512, 512, 1536,
      1, 0, 0, 0, 0, 0, 0, 1);

  // 2) scores[b,h] = Q[b,h] @ K[b,h]^T       [196,196] x 128 batches
  gemm_kernel<<<dim3(4, 4, 128), blk, 0, stream>>>(
      qkv, qkv + 512, scores, nullptr, nullptr,
      196, 196, 64, 1536, 1536, 196,
      8, 196LL * 1536, 64, 196LL * 1536, 64, 8LL * 38416, 38416, 1);

  // 3) softmax rows (scale 0.125 inside)
  softmax_kernel<<<dim3(6272), blk, 0, stream>>>(scores);

  // 4) O[b,h] = P[b,h] @ V[b,h]  -> merged [token, h*64+d]
  gemm_kernel<<<dim3(4, 1, 128), blk, 0, stream>>>(
      scores, qkv + 1024, Omg, nullptr, nullptr,
      196, 64, 196, 196, 1536, 512,
      8, 8LL * 38416, 38416, 196LL * 1536, 64, 196LL * 512, 64, 0);

  // 5) F_enh = O @ Wo^T + bo + F_clean
  gemm_kernel<<<dim3(49, 8, 1), blk, 0, stream>>>(
      Omg, Wo, Fenh, bo, F,
      3136, 512, 512, 512, 512, 512,
      1, 0, 0, 0, 0, 0, 0, 1);

  // 6) h1 = F_enh @ W1^T + b1
  gemm_kernel<<<dim3(49, 8, 1), blk, 0, stream>>>(
      Fenh, W1, h1, b1, nullptr,
      3136, 512, 512, 512, 512, 512,
      1, 0, 0, 0, 0, 0, 0, 1);

  // 7) LayerNorm + exact GELU (in place)
  lngelu_kernel<<<dim3(3136), blk, 0, stream>>>(h1, lng, lnb);

  // 8) Qp = h1 @ W2^T + b2
  w2_kernel<<<dim3(245), blk, 0, stream>>>(h1, W2, b2, Qp);

  // 9) outer product + abs-top-51 mask + L2 normalize + write [B,N,D,M]
  topk_kernel<<<dim3(3136), blk, 0, stream>>>(F, Tm, Qp, out);
}

// Round 2
// 603.319 us; speedup vs baseline: 1.0009x; 1.0009x over previous
//
#include <hip/hip_runtime.h>
#include <cmath>

// ---------------------------------------------------------------------------
// Problem constants: B=16, N=196, D=512, M=20, H=8, hd=64, k=51
//   tokens = 3136, 3D = 1536
// ---------------------------------------------------------------------------

// Generic small GEMM, fp32 storage, fp32 FMA with fp64 chunk accumulation.
// C[i,j] = sum_k A[i,k] * B'[k,j]  (+bias[j]) (+res[i*ldc+j])
//   bTrans=1: B is [N][K] row-major (we dot rows)      -> B'[k,j] = B[j*ldb+k]
//   bTrans=0: B is [K][N] row-major                    -> B'[k,j] = B[k*ldb+j]
// Batched via blockIdx.z: off = (z/zInner)*Outer + (z%zInner)*Inner per operand.
__global__ __launch_bounds__(256) void gemm_kernel(
    const float* __restrict__ A, const float* __restrict__ B,
    float* __restrict__ C, const float* __restrict__ bias,
    const float* __restrict__ res,
    int M, int N, int K, int lda, int ldb, int ldc,
    int zInner, long long aOuter, long long aInner,
    long long bOuter, long long bInner,
    long long cOuter, long long cInner, int bTrans)
{
  int z = blockIdx.z;
  int zo = z / zInner, zi = z % zInner;
  A += zo * aOuter + zi * aInner;
  B += zo * bOuter + zi * bInner;
  C += zo * cOuter + zi * cInner;

  __shared__ __align__(16) float As[16][68];
  __shared__ __align__(16) float Bs[16][68];

  int tid = threadIdx.x;
  int tx = tid & 15, ty = tid >> 4;
  int i0 = blockIdx.x * 64, j0 = blockIdx.y * 64;

  double acc[4][4];
#pragma unroll
  for (int i = 0; i < 4; i++)
#pragma unroll
    for (int j = 0; j < 4; j++) acc[i][j] = 0.0;

  for (int k0 = 0; k0 < K; k0 += 16) {
    // stage A tile [64 rows][16 k] -> As[k][row]
#pragma unroll
    for (int rr = 0; rr < 4; rr++) {
      int r = ty + 16 * rr;
      int gi = i0 + r, gk = k0 + tx;
      As[tx][r] = (gi < M && gk < K) ? A[(size_t)gi * lda + gk] : 0.0f;
    }
    if (bTrans) {
#pragma unroll
      for (int rr = 0; rr < 4; rr++) {
        int r = ty + 16 * rr;
        int gj = j0 + r, gk = k0 + tx;
        Bs[tx][r] = (gj < N && gk < K) ? B[(size_t)gj * ldb + gk] : 0.0f;
      }
    } else {
      int j = tid & 63, c0 = (tid >> 6) * 4;
#pragma unroll
      for (int cc = 0; cc < 4; cc++) {
        int c = c0 + cc;
        int gk = k0 + c, gj = j0 + j;
        Bs[c][j] = (gk < K && gj < N) ? B[(size_t)gk * ldb + gj] : 0.0f;
      }
    }
    __syncthreads();

    float cf[4][4];
#pragma unroll
    for (int i = 0; i < 4; i++)
#pragma unroll
      for (int j = 0; j < 4; j++) cf[i][j] = 0.0f;
#pragma unroll
    for (int kk = 0; kk < 16; kk++) {
      float4 a4 = *(const float4*)&As[kk][ty * 4];
      float4 b4 = *(const float4*)&Bs[kk][tx * 4];
      float av[4] = {a4.x, a4.y, a4.z, a4.w};
      float bv[4] = {b4.x, b4.y, b4.z, b4.w};
#pragma unroll
      for (int i = 0; i < 4; i++)
#pragma unroll
        for (int j = 0; j < 4; j++) cf[i][j] = fmaf(av[i], bv[j], cf[i][j]);
    }
#pragma unroll
    for (int i = 0; i < 4; i++)
#pragma unroll
      for (int j = 0; j < 4; j++) acc[i][j] += (double)cf[i][j];
    __syncthreads();
  }

#pragma unroll
  for (int i = 0; i < 4; i++) {
    int gi = i0 + ty * 4 + i;
    if (gi >= M) continue;
    int gj0 = j0 + tx * 4;
    if (gj0 >= N) continue;  // all our N are multiples of 4
    float ov[4];
#pragma unroll
    for (int j = 0; j < 4; j++) {
      double v = acc[i][j];
      if (bias) v += (double)bias[gj0 + j];
      if (res)  v += (double)res[(size_t)gi * ldc + gj0 + j];
      ov[j] = (float)v;
    }
    float4 o; o.x = ov[0]; o.y = ov[1]; o.z = ov[2]; o.w = ov[3];
    *(float4*)&C[(size_t)gi * ldc + gj0] = o;
  }
}

// In-place row softmax of scaled scores: rows of length 196, scale 1/sqrt(64).
// One wave per row, 4 rows per block. fp64 internal.
__global__ __launch_bounds__(256) void softmax_kernel(float* __restrict__ S)
{
  int row = blockIdx.x * 4 + (threadIdx.x >> 6);
  int lane = threadIdx.x & 63;
  float* sr = S + (size_t)row * 196;
  double v[4];
#pragma unroll
  for (int t = 0; t < 4; t++) {
    int j = lane + 64 * t;
    v[t] = (j < 196) ? (double)sr[j] * 0.125 : -1e300;
  }
  double mx = fmax(fmax(v[0], v[1]), fmax(v[2], v[3]));
#pragma unroll
  for (int off = 1; off < 64; off <<= 1) mx = fmax(mx, __shfl_xor(mx, off));
  double e[4]; double s = 0.0;
#pragma unroll
  for (int t = 0; t < 4; t++) {
    int j = lane + 64 * t;
    e[t] = (j < 196) ? exp(v[t] - mx) : 0.0;
    s += e[t];
  }
#pragma unroll
  for (int off = 1; off < 64; off <<= 1) s += __shfl_xor(s, off);
  double inv = 1.0 / s;
#pragma unroll
  for (int t = 0; t < 4; t++) {
    int j = lane + 64 * t;
    if (j < 196) sr[j] = (float)(e[t] * inv);
  }
}

// In-place LayerNorm (ddof=0, eps=1e-5) + exact GELU over rows of 512.
__global__ __launch_bounds__(256) void lngelu_kernel(float* __restrict__ H,
    const float* __restrict__ g, const float* __restrict__ bb)
{
  int row = blockIdx.x;
  float* hr = H + (size_t)row * 512;
  int tid = threadIdx.x, lane = tid & 63, wv = tid >> 6;
  __shared__ double red[8];
  double x0 = (double)hr[tid], x1 = (double)hr[tid + 256];
  double s = x0 + x1;
#pragma unroll
  for (int off = 1; off < 64; off <<= 1) s += __shfl_xor(s, off);
  if (lane == 0) red[wv] = s;
  __syncthreads();
  double mu = (red[0] + red[1] + red[2] + red[3]) * (1.0 / 512.0);
  double d0 = x0 - mu, d1 = x1 - mu;
  double q = d0 * d0 + d1 * d1;
#pragma unroll
  for (int off = 1; off < 64; off <<= 1) q += __shfl_xor(q, off);
  if (lane == 0) red[4 + wv] = q;
  __syncthreads();
  double var = (red[4] + red[5] + red[6] + red[7]) * (1.0 / 512.0);
  double inv = 1.0 / sqrt(var + 1e-5);
  double y0 = d0 * inv * (double)g[tid]       + (double)bb[tid];
  double y1 = d1 * inv * (double)g[tid + 256] + (double)bb[tid + 256];
  const double ISQRT2 = 0.70710678118654752440;
  double z0 = 0.5 * y0 * (1.0 + erf(y0 * ISQRT2));
  double z1 = 0.5 * y1 * (1.0 + erf(y1 * ISQRT2));
  hr[tid] = (float)z0;
  hr[tid + 256] = (float)z1;
}

// Qp[token,m] = h[token,:] . w2[m,:] + b2[m] ; fp64 accumulate. 62720 outputs.
__global__ __launch_bounds__(256) void w2_kernel(const float* __restrict__ H,
    const float* __restrict__ W2, const float* __restrict__ B2,
    float* __restrict__ Qp)
{
  int gidx = blockIdx.x * 256 + threadIdx.x;  // grid 245*256 == 62720 exactly
  int token = gidx / 20, m = gidx % 20;
  const float* hr = H + (size_t)token * 512;
  const float* wr = W2 + (size_t)m * 512;
  double acc = 0.0;
  for (int k = 0; k < 512; k += 4) {
    float4 hv = *(const float4*)&hr[k];
    float4 wv = *(const float4*)&wr[k];
    acc += (double)hv.x * wv.x + (double)hv.y * wv.y +
           (double)hv.z * wv.z + (double)hv.w * wv.w;
  }
  Qp[gidx] = (float)(acc + (double)B2[m]);
}

// Final: per (b,n,m) abs-top-51 over D of A = (F*T)*Qp, 0/1 mask, L2-normalize,
// write out[b,n,d,m]. Selection key = exact double product |F*T| (bit-exact vs
// a float64 reference), tie-break by lower d via ballot ranks.
__global__ __launch_bounds__(256) void topk_kernel(
    const float* __restrict__ F, const float* __restrict__ T,
    const float* __restrict__ Qp, float* __restrict__ out)
{
  const int KSEL = 51;
  int bn = blockIdx.x;
  int tid = threadIdx.x, lane = tid & 63, wv = tid >> 6;
  __shared__ float tile[512 * 21];  // [d][m], padded row stride 21
  const float* Frow = F + (size_t)bn * 512;
  double f[8];
#pragma unroll
  for (int s = 0; s < 8; s++) f[s] = (double)Frow[lane + 64 * s];

  for (int m = wv; m < 20; m += 4) {
    double qp = (double)Qp[(size_t)bn * 20 + m];
    const float* Trow = T + (size_t)m * 512;
    double a[8];
    unsigned long long u[8];
#pragma unroll
    for (int s = 0; s < 8; s++) {
      double p = f[s] * (double)Trow[lane + 64 * s];  // exact in fp64
      a[s] = p * qp;
      u[s] = ((unsigned long long)__double_as_longlong(p)) & 0x7fffffffffffffffULL;
    }
    // binary search smallest threshold with count(u >= thr) >= 51
    unsigned long long lo = 0ULL, hi = 0x7ff0000000000000ULL;
    while (hi - lo > 1ULL) {
      unsigned long long mid = lo + ((hi - lo) >> 1);
      int c = 0;
#pragma unroll
      for (int s = 0; s < 8; s++) c += (u[s] >= mid) ? 1 : 0;
#pragma unroll
      for (int off = 1; off < 64; off <<= 1) c += __shfl_xor(c, off);
      if (c >= KSEL) { lo = mid; if (c == KSEL) break; }
      else hi = mid;
    }
    unsigned long long thr = lo;
    int cg = 0;
#pragma unroll
    for (int s = 0; s < 8; s++) cg += (u[s] > thr) ? 1 : 0;
#pragma unroll
    for (int off = 1; off < 64; off <<= 1) cg += __shfl_xor(cg, off);
    int need_eq = KSEL - cg;  // how many ==thr to take, in increasing d order
    unsigned long long lmask = (1ULL << lane) - 1ULL;
    bool sel[8];
    int base = 0;
#pragma unroll
    for (int s = 0; s < 8; s++) {   // d = lane + 64*s: (s,lane) lexicographic == d order
      bool iseq = (u[s] == thr);
      unsigned long long bal = __ballot((int)iseq);
      int rk = base + __popcll(bal & lmask);
      sel[s] = (u[s] > thr) || (iseq && rk < need_eq);
      base += __popcll(bal);
    }
    double ss = 0.0;
#pragma unroll
    for (int s = 0; s < 8; s++) if (sel[s]) ss += a[s] * a[s];
#pragma unroll
    for (int off = 1; off < 64; off <<= 1) ss += __shfl_xor(ss, off);
    double inv = 1.0 / fmax(sqrt(ss), 1e-6);
#pragma unroll
    for (int s = 0; s < 8; s++)
      tile[(lane + 64 * s) * 21 + m] = sel[s] ? (float)(a[s] * inv) : 0.0f;
  }
  __syncthreads();

  // coalesced writeout: [512][20] contiguous per (b,n)
  float* orow = out + (size_t)bn * 10240;
#pragma unroll
  for (int it = 0; it < 10; it++) {
    int i = it * 256 + tid;  // float4 index, 2560 total
    int j = i * 4;
    float4 o;
    o.x = tile[((j + 0) / 20) * 21 + (j + 0) % 20];
    o.y = tile[((j + 1) / 20) * 21 + (j + 1) % 20];
    o.z = tile[((j + 2) / 20) * 21 + (j + 2) % 20];
    o.w = tile[((j + 3) / 20) * 21 + (j + 3) % 20];
    *(float4*)&orow[j] = o;
  }
}

extern "C" void kernel_launch(void* const* d_in, const int* in_sizes, int n_in,
                              void* d_out, int out_size, void* d_ws, size_t ws_size,
                              hipStream_t stream) {
  const float* F    = (const float*)d_in[0];   // [3136,512]
  const float* Wqkv = (const float*)d_in[1];   // [1536,512]
  const float* bqkv = (const float*)d_in[2];   // [1536]
  const float* Wo   = (const float*)d_in[3];   // [512,512]
  const float* bo   = (const float*)d_in[4];   // [512]
  const float* W1   = (const float*)d_in[5];   // [512,512]
  const float* b1   = (const float*)d_in[6];   // [512]
  const float* lng  = (const float*)d_in[7];   // [512]
  const float* lnb  = (const float*)d_in[8];   // [512]
  const float* W2   = (const float*)d_in[9];   // [20,512]
  const float* b2   = (const float*)d_in[10];  // [20]
  const float* Tm   = (const float*)d_in[11];  // [20,512]
  float* out = (float*)d_out;

  float* ws     = (float*)d_ws;
  float* qkv    = ws;                    // 3136*1536 = 4,816,896
  float* scores = qkv + 4816896;         // 128*196*196 = 4,917,248
  float* Omg    = scores + 4917248;      // 3136*512
  float* Fenh   = Omg + 1605632;         // 3136*512
  float* h1     = Fenh + 1605632;        // 3136*512
  float* Qp     = h1 + 1605632;          // 3136*20
  dim3 blk(256);

  // 1) qkv = F @ Wqkv^T + bqkv               [3136,1536]
  gemm_kernel<<<dim3(49, 24, 1), blk, 0, stream>>>(
      F, Wqkv, qkv, bqkv, nullptr,
      3136, 1536, 512, 512, 512, 1536,
      1, 0, 0, 0, 0, 0, 0, 1);

  // 2) scores[b,h] = Q[b,h] @ K[b,h]^T       [196,196] x 128 batches
  gemm_kernel<<<dim3(4, 4, 128), blk, 0, stream>>>(
      qkv, qkv + 512, scores, nullptr, nullptr,
      196, 196, 64, 1536, 1536, 196,
      8, 196LL * 1536, 64, 196LL * 1536, 64, 8LL * 38416, 38416, 1);

  // 3) softmax rows (scale 0.125 inside)
  softmax_kernel<<<dim3(6272), blk, 0, stream>>>(scores);

  // 4) O[b,h] = P[b,h] @ V[b,h]  -> merged [token, h*64+d]
  gemm_kernel<<<dim3(4, 1, 128), blk, 0, stream>>>(
      scores, qkv + 1024, Omg, nullptr, nullptr,
      196, 64, 196, 196, 1536, 512,
      8, 8LL * 38416, 38416, 196LL * 1536, 64, 196LL * 512, 64, 0);

  // 5) F_enh = O @ Wo^T + bo + F_clean
  gemm_kernel<<<dim3(49, 8, 1), blk, 0, stream>>>(
      Omg, Wo, Fenh, bo, F,
      3136, 512, 512, 512, 512, 512,
      1, 0, 0, 0, 0, 0, 0, 1);

  // 6) h1 = F_enh @ W1^T + b1
  gemm_kernel<<<dim3(49, 8, 1), blk, 0, stream>>>(
      Fenh, W1, h1, b1, nullptr,
      3136, 512, 512, 512, 512, 512,
      1, 0, 0, 0, 0, 0, 0, 1);

  // 7) LayerNorm + exact GELU (in place)
  lngelu_kernel<<<dim3(3136), blk, 0, stream>>>(h1, lng, lnb);

  // 8) Qp = h1 @ W2^T + b2
  w2_kernel<<<dim3(245), blk, 0, stream>>>(h1, W2, b2, Qp);

  // 9) outer product + abs-top-51 mask + L2 normalize + write [B,N,D,M]
  topk_kernel<<<dim3(3136), blk, 0, stream>>>(F, Tm, Qp, out);
}